// Round 4
// baseline (3023.263 us; speedup 1.0000x reference)
//
#include <hip/hip_runtime.h>
#include <math.h>

#define BS 4096
#define FD 768
#define PD 500
#define ZD 300
#define RNUM 10
#define LBUF (128 * 32)  // shorts per 128x32 bf16 tile (8KB)

typedef short bf16x8 __attribute__((ext_vector_type(8)));
typedef float f32x4 __attribute__((ext_vector_type(4)));

__device__ __forceinline__ unsigned int fbits(float f) {
  union { float f; unsigned int u; } v; v.f = f; return v.u;
}

// pack two fp32 -> two bf16 (round-half-up) in one v_perm
__device__ __forceinline__ unsigned int pack2bf(float f0, float f1) {
  unsigned int u0 = fbits(f0) + 0x8000u;
  unsigned int u1 = fbits(f1) + 0x8000u;
  return __builtin_amdgcn_perm(u1, u0, 0x07060302u);
}

// ---------------------------------------------------------------------------
// fp32 tiled GEMM (kept for the small p2 layer): C = act(A@W^T + b)
// ---------------------------------------------------------------------------
#define BM 128
#define BN 64
#define BK 16
#define TM 8
#define TN 4
template <int ACT>
__global__ __launch_bounds__(256) void gemm_kernel(
    const float* __restrict__ A, const float* __restrict__ W,
    const float* __restrict__ bias, float* __restrict__ C,
    int M, int N, int K) {
  __shared__ float As[BK][BM + 4];
  __shared__ float Bs[BK][BN + 4];
  const int m0 = blockIdx.x * BM;
  const int n0 = blockIdx.y * BN;
  const int tid = threadIdx.x;
  const int tx = tid & 15;
  const int ty = tid >> 4;
  float acc[TM][TN];
#pragma unroll
  for (int i = 0; i < TM; i++)
#pragma unroll
    for (int j = 0; j < TN; j++) acc[i][j] = 0.f;
  const int l_row = tid >> 2;
  const int l_k4 = (tid & 3) * 4;
  for (int k0 = 0; k0 < K; k0 += BK) {
#pragma unroll
    for (int half = 0; half < 2; ++half) {
      int m = m0 + l_row + half * 64;
      int k = k0 + l_k4;
      float4 v = make_float4(0.f, 0.f, 0.f, 0.f);
      if (m < M && k + 4 <= K) v = *(const float4*)(A + (size_t)m * K + k);
      As[l_k4 + 0][l_row + half * 64] = v.x;
      As[l_k4 + 1][l_row + half * 64] = v.y;
      As[l_k4 + 2][l_row + half * 64] = v.z;
      As[l_k4 + 3][l_row + half * 64] = v.w;
    }
    {
      int n = n0 + l_row;
      int k = k0 + l_k4;
      float4 v = make_float4(0.f, 0.f, 0.f, 0.f);
      if (n < N && k + 4 <= K) v = *(const float4*)(W + (size_t)n * K + k);
      Bs[l_k4 + 0][l_row] = v.x;
      Bs[l_k4 + 1][l_row] = v.y;
      Bs[l_k4 + 2][l_row] = v.z;
      Bs[l_k4 + 3][l_row] = v.w;
    }
    __syncthreads();
#pragma unroll
    for (int k = 0; k < BK; k++) {
      float a[TM], b[TN];
#pragma unroll
      for (int i = 0; i < TM; i++) a[i] = As[k][ty * TM + i];
#pragma unroll
      for (int j = 0; j < TN; j++) b[j] = Bs[k][tx * TN + j];
#pragma unroll
      for (int i = 0; i < TM; i++)
#pragma unroll
        for (int j = 0; j < TN; j++) acc[i][j] += a[i] * b[j];
    }
    __syncthreads();
  }
#pragma unroll
  for (int i = 0; i < TM; i++) {
    int m = m0 + ty * TM + i;
    if (m >= M) continue;
#pragma unroll
    for (int j = 0; j < TN; j++) {
      int n = n0 + tx * TN + j;
      if (n >= N) continue;
      float v = acc[i][j] + bias[n];
      if (ACT == 1) v = fmaxf(v, 0.f);
      C[(size_t)m * N + n] = v;
    }
  }
}

// ---------------------------------------------------------------------------
// pad-cast fp32 weight [rs,cs] -> bf16 [rd,cd], zero padded
// ---------------------------------------------------------------------------
__global__ __launch_bounds__(256) void padcast(
    const float* __restrict__ src, unsigned short* __restrict__ dst,
    int rs, int cs, int rd, int cd) {
  int i = blockIdx.x * 256 + threadIdx.x;
  if (i >= rd * cd) return;
  int r = i / cd, c = i - r * cd;
  float v = (r < rs && c < cs) ? src[(size_t)r * cs + c] : 0.f;
  dst[i] = (unsigned short)((fbits(v) + 0x8000u) >> 16);
}

// fused pad-cast for the 6 embed weights [PD,FD] -> [512,FD] each
struct W6 { const float* p[6]; };
__global__ __launch_bounds__(256) void padcast6(W6 w, unsigned short* __restrict__ dst) {
  const int g = blockIdx.y;
  int i = blockIdx.x * 256 + threadIdx.x;  // over 512*FD
  int r = i / FD, c = i - r * FD;
  float v = (r < PD) ? w.p[g][(size_t)r * FD + c] : 0.f;
  dst[(size_t)g * 512 * FD + i] = (unsigned short)((fbits(v) + 0x8000u) >> 16);
}

// ===========================================================================
// bf16 MFMA GEMM core (128x128 tile, 4 waves of 64x64, BK=32).
// Double-buffered LDS (2 x (A 8KB + B 8KB) = 32KB), ONE barrier per K-iter:
//   iter k: barrier; issue global loads k+1; ds_read buf[cur]; 16 MFMA;
//           pack+store buf[cur^1]  (vmcnt wait overlaps ds_read+MFMA)
// XOR-swizzled granules: row r granule kq stored at slot kq^((r>>1)&3)
// -> 2-way-max bank aliasing (free) on both b128 write and read.
// A fp32 in global, converted to bf16 in-register during staging; B pre-cast
// bf16 [Npad][Kp] zero-padded.
// MFMA frag maps (verified): A/B lane row/col=lane&15, k=(lane>>4)*8+i;
// C/D: col=lane&15, row=(lane>>4)*4+reg.
// ===========================================================================

template <int ACT>  // 0=none, 1=relu
__global__ __launch_bounds__(256, 3) void mfma_gemm(
    const float* __restrict__ A, int lda, int Ka,
    const unsigned short* __restrict__ B, int Kp,
    const float* __restrict__ bias, float* __restrict__ C, int Nout) {
  __shared__ unsigned short lds[2][2 * LBUF];
  const int tid = threadIdx.x;
  const int n0 = blockIdx.x * 128;
  const int m0 = blockIdx.y * 128;

  const int arow = tid >> 1;
  const int ahalf = (tid & 1) << 4;
  const int ag = (tid & 1) << 1;
  const int aswz = (arow >> 1) & 3;
  const int awo0 = (arow * 4 + ((ag | 0) ^ aswz)) * 8;
  const int awo1 = (arow * 4 + ((ag | 1) ^ aswz)) * 8;
  const float* aptr = A + (size_t)(m0 + arow) * lda;
  const unsigned short* bptr = B + (size_t)(n0 + arow) * Kp + ag * 8;

  const int lane = tid & 63;
  const int wave = tid >> 6;
  const int wm = (wave >> 1) << 6;
  const int wn = (wave & 1) << 6;
  const int r16 = lane & 15;
  const int kq = lane >> 4;

  int afo[4], bfo[4];
#pragma unroll
  for (int i = 0; i < 4; i++) {
    int rowA = wm + i * 16 + r16;
    afo[i] = (rowA * 4 + (kq ^ ((rowA >> 1) & 3))) * 8;
    int rowB = wn + i * 16 + r16;
    bfo[i] = LBUF + (rowB * 4 + (kq ^ ((rowB >> 1) & 3))) * 8;
  }

  f32x4 acc[4][4] = {};
  float4 f[4];
  uint4 bv0, bv1;

  auto gload = [&](int k0) {
#pragma unroll
    for (int q = 0; q < 4; q++) {
      int k = k0 + ahalf + q * 4;
      if (k < Ka) f[q] = *(const float4*)(aptr + k);
      else f[q] = make_float4(0.f, 0.f, 0.f, 0.f);
    }
    bv0 = *(const uint4*)(bptr + k0);
    bv1 = *(const uint4*)(bptr + k0 + 8);
  };
  auto pstore = [&](unsigned short* L) {
    uint4 w0, w1;
    w0.x = pack2bf(f[0].x, f[0].y); w0.y = pack2bf(f[0].z, f[0].w);
    w0.z = pack2bf(f[1].x, f[1].y); w0.w = pack2bf(f[1].z, f[1].w);
    w1.x = pack2bf(f[2].x, f[2].y); w1.y = pack2bf(f[2].z, f[2].w);
    w1.z = pack2bf(f[3].x, f[3].y); w1.w = pack2bf(f[3].z, f[3].w);
    *(uint4*)(L + awo0) = w0;
    *(uint4*)(L + awo1) = w1;
    *(uint4*)(L + LBUF + awo0) = bv0;
    *(uint4*)(L + LBUF + awo1) = bv1;
  };

  gload(0);
  pstore(lds[0]);
  int cur = 0;
  for (int k0 = 32;; k0 += 32) {
    __syncthreads();
    const bool more = (k0 < Kp);
    if (more) gload(k0);
    const unsigned short* Lc = lds[cur];
    bf16x8 a[4], b[4];
#pragma unroll
    for (int i = 0; i < 4; i++) a[i] = *(const bf16x8*)(Lc + afo[i]);
#pragma unroll
    for (int i = 0; i < 4; i++) b[i] = *(const bf16x8*)(Lc + bfo[i]);
#pragma unroll
    for (int i = 0; i < 4; i++)
#pragma unroll
      for (int j = 0; j < 4; j++)
        acc[i][j] = __builtin_amdgcn_mfma_f32_16x16x32_bf16(a[i], b[j], acc[i][j], 0, 0, 0);
    if (!more) break;
    cur ^= 1;
    pstore(lds[cur]);
  }

#pragma unroll
  for (int j = 0; j < 4; j++) {
    int n = n0 + wn + j * 16 + r16;
    if (n >= Nout) continue;
    float bi = bias[n];
#pragma unroll
    for (int i = 0; i < 4; i++) {
#pragma unroll
      for (int r = 0; r < 4; r++) {
        int m = m0 + wm + i * 16 + kq * 4 + r;
        float v = acc[i][j][r] + bi;
        if (ACT == 1) v = fmaxf(v, 0.f);
        C[(size_t)m * Nout + n] = v;
      }
    }
  }
}

// ---------------------------------------------------------------------------
// Embedding MFMA GEMM: 6 groups in one row space, tanh epilogue.
//   g<3: direct stores to S[g].
//   g>=3: LDS-staged in-block reduction over sample groups of 10 rows;
//         plain store for complete samples (only writer after memset),
//         atomicAdd only for <=2 straddling samples per block.
// ---------------------------------------------------------------------------
struct EmbedArgs {
  const float* A[6];
  const float* bias[6];
};

__global__ __launch_bounds__(256, 3) void embed_mfma(
    EmbedArgs ea, const unsigned short* __restrict__ Wbf,
    float* __restrict__ S, float* __restrict__ E0) {
  __shared__ unsigned short lds[2][2 * LBUF];
  const int tid = threadIdx.x;
  const int n0 = blockIdx.x * 128;
  const int m0 = blockIdx.y * 128;

  int g, base;
  if (m0 < 4096) { g = 0; base = 0; }
  else if (m0 < 8192) { g = 1; base = 4096; }
  else if (m0 < 12288) { g = 2; base = 8192; }
  else if (m0 < 53248) { g = 3; base = 12288; }
  else if (m0 < 94208) { g = 4; base = 53248; }
  else { g = 5; base = 94208; }

  const int arow = tid >> 1;
  const int ahalf = (tid & 1) << 4;
  const int ag = (tid & 1) << 1;
  const int aswz = (arow >> 1) & 3;
  const int awo0 = (arow * 4 + ((ag | 0) ^ aswz)) * 8;
  const int awo1 = (arow * 4 + ((ag | 1) ^ aswz)) * 8;
  const float* aptr = ea.A[g] + (size_t)(m0 - base + arow) * FD;
  const unsigned short* bptr =
      Wbf + (size_t)g * 512 * FD + (size_t)(n0 + arow) * FD + ag * 8;

  const int lane = tid & 63;
  const int wave = tid >> 6;
  const int wm = (wave >> 1) << 6;
  const int wn = (wave & 1) << 6;
  const int r16 = lane & 15;
  const int kq = lane >> 4;

  int afo[4], bfo[4];
#pragma unroll
  for (int i = 0; i < 4; i++) {
    int rowA = wm + i * 16 + r16;
    afo[i] = (rowA * 4 + (kq ^ ((rowA >> 1) & 3))) * 8;
    int rowB = wn + i * 16 + r16;
    bfo[i] = LBUF + (rowB * 4 + (kq ^ ((rowB >> 1) & 3))) * 8;
  }

  f32x4 acc[4][4] = {};
  float4 f[4];
  uint4 bv0, bv1;

  auto gload = [&](int k0) {
#pragma unroll
    for (int q = 0; q < 4; q++) f[q] = *(const float4*)(aptr + k0 + ahalf + q * 4);
    bv0 = *(const uint4*)(bptr + k0);
    bv1 = *(const uint4*)(bptr + k0 + 8);
  };
  auto pstore = [&](unsigned short* L) {
    uint4 w0, w1;
    w0.x = pack2bf(f[0].x, f[0].y); w0.y = pack2bf(f[0].z, f[0].w);
    w0.z = pack2bf(f[1].x, f[1].y); w0.w = pack2bf(f[1].z, f[1].w);
    w1.x = pack2bf(f[2].x, f[2].y); w1.y = pack2bf(f[2].z, f[2].w);
    w1.z = pack2bf(f[3].x, f[3].y); w1.w = pack2bf(f[3].z, f[3].w);
    *(uint4*)(L + awo0) = w0;
    *(uint4*)(L + awo1) = w1;
    *(uint4*)(L + LBUF + awo0) = bv0;
    *(uint4*)(L + LBUF + awo1) = bv1;
  };

  gload(0);
  pstore(lds[0]);
  int cur = 0;
  for (int k0 = 32;; k0 += 32) {
    __syncthreads();
    const bool more = (k0 < FD);
    if (more) gload(k0);
    const unsigned short* Lc = lds[cur];
    bf16x8 a[4], b[4];
#pragma unroll
    for (int i = 0; i < 4; i++) a[i] = *(const bf16x8*)(Lc + afo[i]);
#pragma unroll
    for (int i = 0; i < 4; i++) b[i] = *(const bf16x8*)(Lc + bfo[i]);
#pragma unroll
    for (int i = 0; i < 4; i++)
#pragma unroll
      for (int j = 0; j < 4; j++)
        acc[i][j] = __builtin_amdgcn_mfma_f32_16x16x32_bf16(a[i], b[j], acc[i][j], 0, 0, 0);
    if (!more) break;
    cur ^= 1;
    pstore(lds[cur]);
  }

  const float* bias = ea.bias[g];
  const int base_r = m0 - base;

  if (g < 3) {
#pragma unroll
    for (int j = 0; j < 4; j++) {
      int n = n0 + wn + j * 16 + r16;
      if (n >= PD) continue;
      float bi = bias[n];
#pragma unroll
      for (int i = 0; i < 4; i++)
#pragma unroll
        for (int r = 0; r < 4; r++) {
          int row = wm + i * 16 + kq * 4 + r;
          S[((size_t)g * BS + base_r + row) * PD + n] = tanhf(acc[i][j][r] + bi);
        }
    }
  } else {
    // E0: sample-0 individual rows (first M-tile of groups 3,4 only)
    if (g != 5 && base_r == 0 && wm == 0) {
#pragma unroll
      for (int j = 0; j < 4; j++) {
        int n = n0 + wn + j * 16 + r16;
        if (n >= PD) continue;
        float bi = bias[n];
#pragma unroll
        for (int r = 0; r < 4; r++) {
          int row = kq * 4 + r;  // i == 0 rows
          if (row < 10)
            E0[((size_t)(g - 3) * 10 + row) * PD + n] = tanhf(acc[0][j][r] + bi);
        }
      }
    }
    // in-block reduction over samples (10 rows each), 4 col-chunks of 32
    const int s0 = base_r / 10;
    const int ns = (base_r + 127) / 10 - s0 + 1;  // <= 14
    float* red = (float*)lds;  // 128*32 fp32 = 16KB
    for (int c = 0; c < 4; c++) {
      __syncthreads();
      int jb = (c * 32 - wn) / 16;
      if (jb >= 0 && jb < 4) {
#pragma unroll
        for (int jj = 0; jj < 2; jj++) {
          int j = jb + jj;
          int col = wn + j * 16 + r16;
          int cc = col - c * 32;
          int n = n0 + col;
          float bi = (n < PD) ? bias[n] : 0.f;
#pragma unroll
          for (int i = 0; i < 4; i++)
#pragma unroll
            for (int r = 0; r < 4; r++) {
              int row = wm + i * 16 + kq * 4 + r;
              red[row * 32 + cc] = tanhf(acc[i][j][r] + bi);
            }
        }
      }
      __syncthreads();
      for (int p = tid; p < ns * 32; p += 256) {
        int ls = p >> 5, cc = p & 31;
        int n = n0 + c * 32 + cc;
        if (n >= PD) continue;
        int s = s0 + ls;
        int rlo = s * 10 - base_r;
        int rhi = rlo + 10;
        if (rlo < 0) rlo = 0;
        if (rhi > 128) rhi = 128;
        float sum = 0.f;
        for (int r = rlo; r < rhi; r++) sum += red[r * 32 + cc];
        size_t idx = ((size_t)g * BS + s) * PD + n;
        if (rhi - rlo == 10) S[idx] = sum;       // sole writer
        else atomicAdd(&S[idx], sum);            // straddling sample
      }
    }
  }
}

// ---------------------------------------------------------------------------
// Edge means (fp32): Mn[b*4+e][k]
// ---------------------------------------------------------------------------
__global__ __launch_bounds__(256) void means_kernel(
    const float* __restrict__ S, float* __restrict__ Mn) {
  const int total = 4 * BS * PD;
  for (int i = blockIdx.x * blockDim.x + threadIdx.x; i < total;
       i += gridDim.x * blockDim.x) {
    int m = i / PD;
    int k = i - m * PD;
    int b = m >> 2, e = m & 3;
    float v;
    const size_t o = (size_t)b * PD + k;
    if (e == 0)
      v = (S[o] + S[(size_t)BS * PD + o] + S[2 * (size_t)BS * PD + o]) * (1.f / 3.f);
    else if (e == 1)
      v = (S[3 * (size_t)BS * PD + o] + S[o]) * (1.f / 11.f);
    else if (e == 2)
      v = (S[4 * (size_t)BS * PD + o] + S[(size_t)BS * PD + o]) * (1.f / 11.f);
    else
      v = (S[5 * (size_t)BS * PD + o] + S[2 * (size_t)BS * PD + o]) * (1.f / 11.f);
    Mn[i] = v;
  }
}

// ---------------------------------------------------------------------------
__global__ __launch_bounds__(256) void xte_kernel(
    const float* __restrict__ E0, const float* __restrict__ hg_w,
    const float* __restrict__ hg_b, float* __restrict__ XtE) {
  const int i = blockIdx.x;  // 0..19
  __shared__ float row[PD];
  for (int k = threadIdx.x; k < PD; k += 256) row[k] = E0[(size_t)i * PD + k];
  __syncthreads();
  for (int n = threadIdx.x; n < ZD; n += 256) {
    float s = 0.f;
    const float* w = hg_w + (size_t)n * PD;
    for (int k = 0; k < PD; k++) s += row[k] * w[k];
    XtE[(size_t)i * ZD + n] = s + hg_b[n];
  }
}

// ---------------------------------------------------------------------------
__global__ __launch_bounds__(256) void feat_kernel(
    const float* __restrict__ Y, const float* __restrict__ XtE,
    const float* __restrict__ sim_in, const float* __restrict__ label,
    const float* __restrict__ lbl_w, const float* __restrict__ lbl_b,
    float* __restrict__ feat) {
  const int b = blockIdx.x;
  __shared__ float w[RNUM];
  __shared__ float lbl_agg_s;
  if (threadIdx.x == 0) {
    float s[RNUM], mx = -1e30f;
    for (int r = 0; r < RNUM; r++) {
      s[r] = sim_in[(size_t)b * RNUM + r];
      mx = fmaxf(mx, s[r]);
    }
    float sum = 0.f;
    for (int r = 0; r < RNUM; r++) { s[r] = expf(s[r] - mx); sum += s[r]; }
    float la = 0.f;
    for (int r = 0; r < RNUM; r++) {
      w[r] = s[r] / sum;
      la += w[r] * label[(size_t)b * RNUM + r];
    }
    lbl_agg_s = la;
  }
  __syncthreads();
  const float* Yb = Y + (size_t)b * 4 * ZD;
  float* fb = feat + (size_t)b * 7 * ZD;
  const float la = lbl_agg_s;
  for (int n = threadIdx.x; n < ZD; n += blockDim.x) {
    float y0 = Yb[n], y1 = Yb[ZD + n], y2 = Yb[2 * ZD + n], y3 = Yb[3 * ZD + n];
    fb[n] = fmaxf(0.5f * (y0 + y1), 0.f);
    fb[ZD + n] = fmaxf(0.5f * (y0 + y2), 0.f);
    fb[2 * ZD + n] = fmaxf(0.5f * (y0 + y3), 0.f);
    float rv, rt;
    if (b == 0) {
      rv = 0.f; rt = 0.f;
      for (int r = 0; r < RNUM; r++) {
        float yp = 0.5f * (XtE[(size_t)r * ZD + n] + XtE[(size_t)(10 + r) * ZD + n]);
        rt += w[r] * fmaxf(0.5f * (y1 + yp), 0.f);
        rv += w[r] * fmaxf(0.5f * (y2 + yp), 0.f);
      }
    } else {
      rt = fmaxf(y1, 0.f);
      rv = fmaxf(y2, 0.f);
    }
    fb[3 * ZD + n] = rv;
    fb[4 * ZD + n] = rt;
    fb[5 * ZD + n] = fmaxf(y3, 0.f);
    fb[6 * ZD + n] = fmaxf(la * lbl_w[n] + lbl_b[n], 0.f);
  }
}

// ---------------------------------------------------------------------------
__global__ __launch_bounds__(256) void head_kernel(
    const float* __restrict__ h2, const float* __restrict__ p3_w,
    const float* __restrict__ p3_b, float* __restrict__ out) {
  const int wave = (blockIdx.x * blockDim.x + threadIdx.x) >> 6;
  const int lane = threadIdx.x & 63;
  if (wave >= BS) return;
  const float* row = h2 + (size_t)wave * 200;
  float s = 0.f;
  for (int k = lane; k < 200; k += 64) s += row[k] * p3_w[k];
#pragma unroll
  for (int off = 32; off; off >>= 1) s += __shfl_down(s, off, 64);
  if (lane == 0) out[wave] = 1.f / (1.f + expf(-(s + p3_b[0])));
}

// ---------------------------------------------------------------------------
extern "C" void kernel_launch(void* const* d_in, const int* in_sizes, int n_in,
                              void* d_out, int out_size, void* d_ws,
                              size_t ws_size, hipStream_t stream) {
  (void)in_sizes; (void)n_in; (void)out_size; (void)ws_size;

  const float* visual = (const float*)d_in[0];
  const float* textual = (const float*)d_in[1];
  const float* similarity = (const float*)d_in[2];
  const float* r_visual = (const float*)d_in[3];
  const float* r_textual = (const float*)d_in[4];
  const float* r_label = (const float*)d_in[5];
  const float* user = (const float*)d_in[6];
  const float* r_user = (const float*)d_in[7];
  const float* vis_w = (const float*)d_in[9];
  const float* vis_b = (const float*)d_in[10];
  const float* txt_w = (const float*)d_in[11];
  const float* txt_b = (const float*)d_in[12];
  const float* usr_w = (const float*)d_in[13];
  const float* usr_b = (const float*)d_in[14];
  const float* rvis_w = (const float*)d_in[15];
  const float* rvis_b = (const float*)d_in[16];
  const float* rtxt_w = (const float*)d_in[17];
  const float* rtxt_b = (const float*)d_in[18];
  const float* rusr_w = (const float*)d_in[19];
  const float* rusr_b = (const float*)d_in[20];
  const float* hg_w = (const float*)d_in[21];
  const float* hg_b = (const float*)d_in[22];
  const float* lbl_w = (const float*)d_in[23];
  const float* lbl_b = (const float*)d_in[24];
  const float* p1_w = (const float*)d_in[25];
  const float* p1_b = (const float*)d_in[26];
  const float* p2_w = (const float*)d_in[27];
  const float* p2_b = (const float*)d_in[28];
  const float* p3_w = (const float*)d_in[29];
  const float* p3_b = (const float*)d_in[30];
  float* out = (float*)d_out;

  // workspace layout
  float* ws = (float*)d_ws;
  float* S = ws;                            // 6*4096*500
  float* E0 = S + (size_t)6 * BS * PD;      // 20*500
  float* XtE = E0 + 20 * PD;                // 20*300
  float* Mn = XtE + 20 * ZD;                // 16384*500
  float* Y = Mn + (size_t)4 * BS * PD;      // 16384*300
  float* feat = Y + (size_t)4 * BS * ZD;    // 4096*2100
  float* h1 = feat + (size_t)BS * 7 * ZD;   // 4096*800
  float* h2 = h1 + (size_t)BS * 800;        // 4096*200
  unsigned short* Wbf = (unsigned short*)(h2 + (size_t)BS * 200);  // 6*512*768
  unsigned short* hgwbf = Wbf + (size_t)6 * 512 * FD;              // 384*512
  unsigned short* p1wbf = hgwbf + (size_t)384 * 512;               // 896*2112

  // pre-cast weights to zero-padded bf16
  W6 w6;
  w6.p[0] = txt_w; w6.p[1] = vis_w; w6.p[2] = usr_w;
  w6.p[3] = rtxt_w; w6.p[4] = rvis_w; w6.p[5] = rusr_w;
  padcast6<<<dim3(512 * FD / 256, 6), 256, 0, stream>>>(w6, Wbf);
  padcast<<<(384 * 512 + 255) / 256, 256, 0, stream>>>(hg_w, hgwbf, ZD, PD, 384, 512);
  padcast<<<(896 * 2112 + 255) / 256, 256, 0, stream>>>(p1_w, p1wbf, 800, 2100, 896, 2112);

  // zero S[3..5] (base for straddle atomics; complete samples plain-store)
  hipMemsetAsync(S + (size_t)3 * BS * PD, 0, (size_t)3 * BS * PD * sizeof(float),
                 stream);

  EmbedArgs ea;
  ea.A[0] = textual;  ea.bias[0] = txt_b;
  ea.A[1] = visual;   ea.bias[1] = vis_b;
  ea.A[2] = user;     ea.bias[2] = usr_b;
  ea.A[3] = r_textual; ea.bias[3] = rtxt_b;
  ea.A[4] = r_visual;  ea.bias[4] = rvis_b;
  ea.A[5] = r_user;    ea.bias[5] = rusr_b;

  // grid: N-tiles fastest so blocks sharing an A M-tile are adjacent (L2 reuse)
  embed_mfma<<<dim3(4, 135168 / 128), 256, 0, stream>>>(ea, Wbf, S, E0);
  xte_kernel<<<20, 256, 0, stream>>>(E0, hg_w, hg_b, XtE);
  means_kernel<<<4096, 256, 0, stream>>>(S, Mn);
  mfma_gemm<0><<<dim3(3, 16384 / 128), 256, 0, stream>>>(
      Mn, PD, PD, hgwbf, 512, hg_b, Y, ZD);
  feat_kernel<<<BS, 256, 0, stream>>>(Y, XtE, similarity, r_label, lbl_w, lbl_b,
                                      feat);
  mfma_gemm<1><<<dim3(7, BS / 128), 256, 0, stream>>>(
      feat, 2100, 2100, p1wbf, 2112, p1_b, h1, 800);
  gemm_kernel<1><<<dim3(BS / BM, (200 + BN - 1) / BN), 256, 0, stream>>>(
      h1, p2_w, p2_b, h2, BS, 200, 800);
  head_kernel<<<BS * 64 / 256, 256, 0, stream>>>(h2, p3_w, p3_b, out);
}